// Round 4
// baseline (6950.382 us; speedup 1.0000x reference)
//
#include <hip/hip_runtime.h>
#include <stdint.h>

#define T_ 1024
#define B_ 64
#define I_ 256
#define H_ 512
#define O_ 5
#define NCHAIN 8
#define NB 8             // batches per chain
#define JW 16            // hidden columns per WG
#define GRID_MAIN 256    // 8 chains x 32 WGs; chain = wg % 8 (XCD-local under rr)
#define BLOCK_MAIN 256
#define XBS 264          // xbuf row stride in u16 (256 + 8 pad)
#define FLAGS_BYTES 4096
#define BH (B_*H_)
#define TBO (T_*B_*O_)

typedef __bf16 bf16x8 __attribute__((ext_vector_type(8)));
typedef float floatx4 __attribute__((ext_vector_type(4)));
typedef unsigned short u16;
typedef unsigned short u16x8 __attribute__((ext_vector_type(8)));
typedef unsigned int u32;
typedef u32 u32x4 __attribute__((ext_vector_type(4)));

__device__ __forceinline__ u16 f2bf(float f) {
  unsigned int u = __float_as_uint(f);
  u += 0x7fffu + ((u >> 16) & 1u);   // RNE
  return (u16)(u >> 16);
}
__device__ __forceinline__ float bf2f(u16 v) {
  return __uint_as_float(((unsigned int)v) << 16);
}
__device__ __forceinline__ float sigmoid_f(float x) {
  return 1.0f / (1.0f + __expf(-x));
}
__device__ __forceinline__ float tanh_f(float x) {
  return 2.0f / (1.0f + __expf(-2.0f * x)) - 1.0f;
}

// ---- cache-policy-controlled accesses (gfx950 sc0/sc1 bits) ----
// sc0 load: bypass L1, served by (XCD-local) L2. sc0 sc1 load: L3/memory.
__device__ __forceinline__ u32 load_u32_sc0(const u32* p) {
  u32 v;
  asm volatile("global_load_dword %0, %1, off sc0\n\ts_waitcnt vmcnt(0)"
               : "=v"(v) : "v"(p) : "memory");
  return v;
}
__device__ __forceinline__ u32 load_u32_sc1(const u32* p) {
  u32 v;
  asm volatile("global_load_dword %0, %1, off sc0 sc1\n\ts_waitcnt vmcnt(0)"
               : "=v"(v) : "v"(p) : "memory");
  return v;
}
__device__ __forceinline__ void store_u32_plain(u32* p, u32 v) {
  asm volatile("global_store_dword %0, %1, off" :: "v"(p), "v"(v) : "memory");
}
__device__ __forceinline__ void store_u32_sc01(u32* p, u32 v) {
  asm volatile("global_store_dword %0, %1, off sc0 sc1" :: "v"(p), "v"(v) : "memory");
}

// 4-chunk (w==1) and 6-chunk (w==2,3) bulk payload loads: all loads issued,
// ONE vmcnt wait (1 RT, not N). Chunk stride = 32 u32 = 128 B.
#define H8_BODY(SC) \
    "global_load_dwordx4 %0, %8, off " SC "\n\t" \
    "global_load_dwordx4 %1, %8, off offset:16 " SC "\n\t" \
    "global_load_dwordx4 %2, %8, off offset:128 " SC "\n\t" \
    "global_load_dwordx4 %3, %8, off offset:144 " SC "\n\t" \
    "global_load_dwordx4 %4, %8, off offset:256 " SC "\n\t" \
    "global_load_dwordx4 %5, %8, off offset:272 " SC "\n\t" \
    "global_load_dwordx4 %6, %8, off offset:384 " SC "\n\t" \
    "global_load_dwordx4 %7, %8, off offset:400 " SC "\n\t" \
    "s_waitcnt vmcnt(0)"
__device__ __forceinline__ void load_h8_sc0(const u32* p, u32x4* r) {
  asm volatile(H8_BODY("sc0")
    : "=v"(r[0]), "=v"(r[1]), "=v"(r[2]), "=v"(r[3]),
      "=v"(r[4]), "=v"(r[5]), "=v"(r[6]), "=v"(r[7])
    : "v"(p) : "memory");
}
__device__ __forceinline__ void load_h8_sc1(const u32* p, u32x4* r) {
  asm volatile(H8_BODY("sc0 sc1")
    : "=v"(r[0]), "=v"(r[1]), "=v"(r[2]), "=v"(r[3]),
      "=v"(r[4]), "=v"(r[5]), "=v"(r[6]), "=v"(r[7])
    : "v"(p) : "memory");
}
#define H12_BODY(SC) \
    "global_load_dwordx4 %0, %12, off " SC "\n\t" \
    "global_load_dwordx4 %1, %12, off offset:16 " SC "\n\t" \
    "global_load_dwordx4 %2, %12, off offset:128 " SC "\n\t" \
    "global_load_dwordx4 %3, %12, off offset:144 " SC "\n\t" \
    "global_load_dwordx4 %4, %12, off offset:256 " SC "\n\t" \
    "global_load_dwordx4 %5, %12, off offset:272 " SC "\n\t" \
    "global_load_dwordx4 %6, %12, off offset:384 " SC "\n\t" \
    "global_load_dwordx4 %7, %12, off offset:400 " SC "\n\t" \
    "global_load_dwordx4 %8, %12, off offset:512 " SC "\n\t" \
    "global_load_dwordx4 %9, %12, off offset:528 " SC "\n\t" \
    "global_load_dwordx4 %10, %12, off offset:640 " SC "\n\t" \
    "global_load_dwordx4 %11, %12, off offset:656 " SC "\n\t" \
    "s_waitcnt vmcnt(0)"
__device__ __forceinline__ void load_h12_sc0(const u32* p, u32x4* r) {
  asm volatile(H12_BODY("sc0")
    : "=v"(r[0]), "=v"(r[1]), "=v"(r[2]), "=v"(r[3]), "=v"(r[4]), "=v"(r[5]),
      "=v"(r[6]), "=v"(r[7]), "=v"(r[8]), "=v"(r[9]), "=v"(r[10]), "=v"(r[11])
    : "v"(p) : "memory");
}
__device__ __forceinline__ void load_h12_sc1(const u32* p, u32x4* r) {
  asm volatile(H12_BODY("sc0 sc1")
    : "=v"(r[0]), "=v"(r[1]), "=v"(r[2]), "=v"(r[3]), "=v"(r[4]), "=v"(r[5]),
      "=v"(r[6]), "=v"(r[7]), "=v"(r[8]), "=v"(r[9]), "=v"(r[10]), "=v"(r[11])
    : "v"(p) : "memory");
}

// stage bf16(x[ts]) slice (8 batches x 256) into LDS xbuf slot; u in [0,128)
__device__ __forceinline__ void stage_x(const float* __restrict__ xsrc,
                                        u16 (*xb)[XBS], int u) {
  #pragma unroll
  for (int i = 0; i < 2; ++i) {
    int cid = u + 128 * i;          // 256 chunks of 8 floats
    int b  = cid >> 5;
    int ko = (cid & 31) * 8;
    const float4* s = (const float4*)(xsrc + (size_t)b * I_ + ko);
    float4 f0 = s[0], f1 = s[1];
    u16x8 uu;
    uu[0]=f2bf(f0.x); uu[1]=f2bf(f0.y); uu[2]=f2bf(f0.z); uu[3]=f2bf(f0.w);
    uu[4]=f2bf(f1.x); uu[5]=f2bf(f1.y); uu[6]=f2bf(f1.z); uu[7]=f2bf(f1.w);
    *(u16x8*)&xb[b][ko] = uu;
  }
}

// Persistent LSTM. 8 XCD-local chains (8 batches) x 32 WGs; W register-resident.
// Exchange: producer double-store (plain -> fresh dirty line in local L2;
// sc0|sc1 -> fresh in L3). Consumer: cheap per-WG flag poll (sc0, L2-served;
// every 8th try sc1 for mapping robustness), then ONE bulk tagged payload read
// (sc0) self-validated by tags; tag mismatch escalates to sc1. Correct under
// any block->XCD mapping; fast when chain is XCD-local (%8 round-robin).
__global__ __launch_bounds__(BLOCK_MAIN, 1)
void lstm_persistent(const float* __restrict__ x,
                     const float* __restrict__ W_ih,
                     const float* __restrict__ W_hh,
                     const float* __restrict__ b_ih,
                     const float* __restrict__ b_hh,
                     float* __restrict__ out,
                     u32* __restrict__ flagbase,  // [chain][64] u32
                     u32* __restrict__ ex,        // [2][B_][H_] tagged u32
                     u16* __restrict__ hist)      // [(T_+1)][B_][H_] bf16
{
  __shared__ __align__(16) u16 xbuf[2][NB][XBS];
  __shared__ float part[4 * 4 * 16 * 17];         // [w][gate][j16][n(+pad)]

  const int tid   = threadIdx.x;
  const int wg    = blockIdx.x;
  const int chain = wg & 7;         // = XCD id under round-robin
  const int jslot = wg >> 3;        // 0..31 within chain
  const int jbase = jslot * JW;
  const int bbase = chain * NB;
  const int w     = tid >> 6;       // wave id = K-quarter
  const int lane  = tid & 63;
  const int q     = lane >> 4;
  const int n     = lane & 15;

  // ---- W -> register A-fragments (A[m=lane&15][k=q*8+i]), once ----
  bf16x8 afrag[4][6];
  #pragma unroll
  for (int g = 0; g < 4; ++g) {
    #pragma unroll
    for (int kk = 0; kk < 6; ++kk) {
      const int kc  = w * 6 + kk;                 // K-chunk of 32
      const int row = g * H_ + jbase + n;         // gate row in [0,2048)
      const float* src;
      if (kc < 8) src = W_ih + (size_t)row * I_ + kc * 32 + q * 8;
      else        src = W_hh + (size_t)row * H_ + (kc - 8) * 32 + q * 8;
      float4 f0 = ((const float4*)src)[0];
      float4 f1 = ((const float4*)src)[1];
      bf16x8 a;
      a[0]=(__bf16)f0.x; a[1]=(__bf16)f0.y; a[2]=(__bf16)f0.z; a[3]=(__bf16)f0.w;
      a[4]=(__bf16)f1.x; a[5]=(__bf16)f1.y; a[6]=(__bf16)f1.z; a[7]=(__bf16)f1.w;
      afrag[g][kk] = a;
    }
  }

  // ---- elementwise identity: threads 0..127 own (eb in [0,8), ej in [0,16)) ----
  const int eb = tid >> 4;
  const int ej = tid & 15;
  float bias[4];
  float cval = 0.0f;
  if (tid < 128) {
    #pragma unroll
    for (int g = 0; g < 4; ++g)
      bias[g] = b_ih[g * H_ + jbase + ej] + b_hh[g * H_ + jbase + ej];
  }

  u32* flags = flagbase + chain * 64;             // 32 words used
  const int nx = (w == 0) ? 6 : ((w == 1) ? 2 : 0);
  const int hoff = (w == 2) ? 128 : ((w == 3) ? 320 : 0);  // first h j-index

  // ---- pre-stage x_0 ----
  if (tid >= 128) stage_x(x + (size_t)bbase * I_, xbuf[0], tid - 128);
  __syncthreads();

  for (int t = 0; t < T_; ++t) {
    const int sr = t & 1, sw = (t + 1) & 1;

    bf16x8 bfrag[6];
    // x-chunks from LDS (staged during the previous step)
    #pragma unroll
    for (int kk = 0; kk < 6; ++kk)
      if (kk < nx)
        bfrag[kk] = __builtin_bit_cast(bf16x8,
            *(const uint4*)&xbuf[sr][n & 7][(w * 6 + kk) * 32 + q * 8]);

    if (w > 0) {
      // ---- flag wait: 1 dword/lane, L2-served ----
      {
        const u32* fp = flags + (lane & 31);
        int tries = 0;
        for (;;) {
          u32 f = (((++tries) & 7) == 0) ? load_u32_sc1(fp) : load_u32_sc0(fp);
          if (__all((int)(f >= (u32)t))) break;
          __builtin_amdgcn_s_sleep(1);
        }
      }
      // ---- ONE bulk tagged payload read; escalate to sc1 on tag mismatch ----
      const u32 tp = (u32)t << 16;
      const u32* hp = ex + (size_t)sr * BH + (size_t)(bbase + (n & 7)) * H_ +
                      hoff + q * 8;
      u32x4 r[12];
      const int nv = (w == 1) ? 8 : 12;
      int tries = 0;
      for (;;) {
        if (tries >= 2) { if (w == 1) load_h8_sc1(hp, r); else load_h12_sc1(hp, r); }
        else            { if (w == 1) load_h8_sc0(hp, r); else load_h12_sc0(hp, r); }
        u32 bad = 0;
        for (int i = 0; i < nv; ++i)
          bad |= (r[i][0]^tp) | (r[i][1]^tp) | (r[i][2]^tp) | (r[i][3]^tp);
        bad &= 0xFFFF0000u;
        if (!__any((int)(bad != 0u))) break;
        ++tries;
        __builtin_amdgcn_s_sleep(1);
      }
      // unpack tagged words -> bf16 B-fragments
      #pragma unroll
      for (int kk = 0; kk < 6; ++kk) {
        if (kk >= nx) {
          const int ii = (kk - nx) * 2;
          u32x4 a = r[ii], b = r[ii + 1];
          u32x4 pk;
          pk[0] = (a[0] & 0xFFFFu) | (a[1] << 16);
          pk[1] = (a[2] & 0xFFFFu) | (a[3] << 16);
          pk[2] = (b[0] & 0xFFFFu) | (b[1] << 16);
          pk[3] = (b[2] & 0xFFFFu) | (b[3] << 16);
          bfrag[kk] = __builtin_bit_cast(bf16x8, pk);
        }
      }
    }

    // ---- MFMA partial gates over this wave's K-quarter ----
    floatx4 acc[4] = {};
    #pragma unroll
    for (int kk = 0; kk < 6; ++kk) {
      #pragma unroll
      for (int g = 0; g < 4; ++g)
        acc[g] = __builtin_amdgcn_mfma_f32_16x16x32_bf16(afrag[g][kk], bfrag[kk], acc[g], 0, 0, 0);
    }

    // write partial C tiles (C: col=lane&15=batch, row=q*4+reg=j)
    #pragma unroll
    for (int g = 0; g < 4; ++g)
      #pragma unroll
      for (int r = 0; r < 4; ++r)
        part[((w * 4 + g) * 16 + (q * 4 + r)) * 17 + n] = acc[g][r];
    __syncthreads();

    if (tid < 128) {
      // ---- reduce 4 K-partials, gates -> c,h ; publish tagged h ----
      float gate[4];
      #pragma unroll
      for (int g = 0; g < 4; ++g) {
        float s = bias[g];
        #pragma unroll
        for (int w2 = 0; w2 < 4; ++w2)
          s += part[((w2 * 4 + g) * 16 + ej) * 17 + eb];
        gate[g] = s;
      }
      const float ig = sigmoid_f(gate[0]);
      const float fg = sigmoid_f(gate[1]);
      const float gg = tanh_f(gate[2]);
      const float og = sigmoid_f(gate[3]);
      cval = fg * cval + ig * gg;
      const float hval = og * tanh_f(cval);
      const int bg = bbase + eb;
      const int jg = jbase + ej;
      const u32 tagv = ((u32)(t + 1) << 16) | (u32)f2bf(hval);
      u32* exw = ex + (size_t)sw * BH + (size_t)bg * H_ + jg;
      store_u32_plain(exw, tagv);   // fresh (dirty) in local L2 -> fast local read
      store_u32_sc01(exw, tagv);    // write-through to L3 -> cross-XCD safe
      hist[(size_t)(t + 1) * BH + (size_t)bg * H_ + jg] = f2bf(hval);
      if (t == T_ - 1) {
        out[TBO + (size_t)bg * H_ + jg]      = hval;   // h_T
        out[TBO + BH + (size_t)bg * H_ + jg] = cval;   // c_T
      }
    } else {
      // ---- waves 2,3: pre-stage x_{t+1} ----
      const int ts = (t + 1 < T_) ? (t + 1) : (T_ - 1);
      stage_x(x + ((size_t)ts * B_ + bbase) * I_, xbuf[sw], tid - 128);
    }
    __syncthreads();   // drains all payload stores (vmcnt) before flag
    if (tid == 0) {
      store_u32_plain(&flags[jslot], (u32)(t + 1));
      store_u32_sc01(&flags[jslot], (u32)(t + 1));
    }
  }
}

// outputs[t,b,:] = h_t @ fc_w^T + fc_b ; one wave per (t,b) row
__global__ __launch_bounds__(256)
void fc_kernel(const u16* __restrict__ hist,
               const float* __restrict__ fc_w,
               const float* __restrict__ fc_b,
               float* __restrict__ out)
{
  const int gw   = (blockIdx.x * 256 + threadIdx.x) >> 6;
  const int lane = threadIdx.x & 63;
  const int t = gw >> 6;
  const int b = gw & 63;
  const u16* hrow = hist + ((size_t)(t + 1) * B_ + b) * H_ + lane * 8;
  uint4 hv = *(const uint4*)hrow;
  float h[8];
  {
    u16x8 hu = __builtin_bit_cast(u16x8, hv);
    #pragma unroll
    for (int i = 0; i < 8; ++i) h[i] = bf2f(hu[i]);
  }
  float accs[O_];
  #pragma unroll
  for (int o = 0; o < O_; ++o) {
    const float* wr = fc_w + (size_t)o * H_ + lane * 8;
    float4 w0 = ((const float4*)wr)[0];
    float4 w1 = ((const float4*)wr)[1];
    accs[o] = h[0]*w0.x + h[1]*w0.y + h[2]*w0.z + h[3]*w0.w
            + h[4]*w1.x + h[5]*w1.y + h[6]*w1.z + h[7]*w1.w;
  }
  #pragma unroll
  for (int o = 0; o < O_; ++o)
    #pragma unroll
    for (int off = 32; off > 0; off >>= 1)
      accs[o] += __shfl_down(accs[o], off, 64);
  if (lane == 0) {
    #pragma unroll
    for (int o = 0; o < O_; ++o)
      out[((size_t)t * B_ + b) * O_ + o] = accs[o] + fc_b[o];
  }
}

extern "C" void kernel_launch(void* const* d_in, const int* in_sizes, int n_in,
                              void* d_out, int out_size, void* d_ws, size_t ws_size,
                              hipStream_t stream)
{
  (void)in_sizes; (void)n_in; (void)out_size; (void)ws_size;
  const float* x    = (const float*)d_in[0];
  const float* W_ih = (const float*)d_in[1];
  const float* W_hh = (const float*)d_in[2];
  const float* b_ih = (const float*)d_in[3];
  const float* b_hh = (const float*)d_in[4];
  const float* fc_w = (const float*)d_in[5];
  const float* fc_b = (const float*)d_in[6];
  float* out = (float*)d_out;

  u32* flags = (u32*)d_ws;                                  // 8 x 256 B
  u32* ex    = (u32*)((char*)d_ws + FLAGS_BYTES);           // 2*BH u32 = 256 KB
  u16* hist  = (u16*)((char*)d_ws + FLAGS_BYTES + 2 * BH * 4);

  // zero flags + both ex slots (slot0 = tag 0 / h0 = 0; clears stale tags)
  hipMemsetAsync(d_ws, 0, FLAGS_BYTES + 2 * BH * 4, stream);

  lstm_persistent<<<GRID_MAIN, BLOCK_MAIN, 0, stream>>>(
      x, W_ih, W_hh, b_ih, b_hh, out, flags, ex, hist);
  fc_kernel<<<(T_ * B_) / 4, 256, 0, stream>>>(hist, fc_w, fc_b, out);
}

// Round 7
// 2682.430 us; speedup vs baseline: 2.5911x; 2.5911x over previous
//
#include <hip/hip_runtime.h>
#include <stdint.h>

#define T_ 1024
#define B_ 64
#define I_ 256
#define H_ 512
#define O_ 5
#define NCHAIN 8
#define NB 8             // batches per chain
#define JW 16            // hidden columns per WG
#define GRID_MAIN 256    // 8 chains x 32 WGs (chain = wg&7, jslot = wg>>3)
#define BLOCK_MAIN 256
#define XBS 264          // xbuf row stride in u16 (256 + 8 pad)
#define EX_OFF 4096      // ex offset in ws (bytes)
#define BH (B_*H_)
#define TBO (T_*B_*O_)

typedef __bf16 bf16x8 __attribute__((ext_vector_type(8)));
typedef float floatx4 __attribute__((ext_vector_type(4)));
typedef unsigned short u16;
typedef unsigned short u16x8 __attribute__((ext_vector_type(8)));
typedef unsigned int u32;
typedef u32 u32x4 __attribute__((ext_vector_type(4)));

__device__ __forceinline__ u16 f2bf(float f) {
  unsigned int u = __float_as_uint(f);
  u += 0x7fffu + ((u >> 16) & 1u);   // RNE
  return (u16)(u >> 16);
}
__device__ __forceinline__ float bf2f(u16 v) {
  return __uint_as_float(((unsigned int)v) << 16);
}
__device__ __forceinline__ float sigmoid_f(float x) {
  return 1.0f / (1.0f + __expf(-x));
}
__device__ __forceinline__ float tanh_f(float x) {
  return 2.0f / (1.0f + __expf(-2.0f * x)) - 1.0f;
}

// ---- L3-coherent exchange primitives (sc0 sc1 = bypass L1/L2, coherence
// point is the memory-side Infinity Cache). Proven deadlock-free in R2/R3/R4.
__device__ __forceinline__ u32 load_u32_l3(const u32* p) {
  u32 v;
  asm volatile("global_load_dword %0, %1, off sc0 sc1\n\ts_waitcnt vmcnt(0)"
               : "=v"(v) : "v"(p) : "memory");
  return v;
}
__device__ __forceinline__ void store_u32_l3(u32* p, u32 v) {
  asm volatile("global_store_dword %0, %1, off sc0 sc1" :: "v"(p), "v"(v) : "memory");
}

// bulk B-fragment loads (bf16-packed ex, one K-chunk = 32 h = 64 B/batch-row):
// issue all dwordx4 then ONE vmcnt (1 L3 round trip, not N).
__device__ __forceinline__ void load_h4_l3(const u16* p, u32x4* r) {
  asm volatile(
    "global_load_dwordx4 %0, %4, off sc0 sc1\n\t"
    "global_load_dwordx4 %1, %4, off offset:64 sc0 sc1\n\t"
    "global_load_dwordx4 %2, %4, off offset:128 sc0 sc1\n\t"
    "global_load_dwordx4 %3, %4, off offset:192 sc0 sc1\n\t"
    "s_waitcnt vmcnt(0)"
    : "=&v"(r[0]), "=&v"(r[1]), "=&v"(r[2]), "=&v"(r[3]) : "v"(p) : "memory");
}
__device__ __forceinline__ void load_h6_l3(const u16* p, u32x4* r) {
  asm volatile(
    "global_load_dwordx4 %0, %6, off sc0 sc1\n\t"
    "global_load_dwordx4 %1, %6, off offset:64 sc0 sc1\n\t"
    "global_load_dwordx4 %2, %6, off offset:128 sc0 sc1\n\t"
    "global_load_dwordx4 %3, %6, off offset:192 sc0 sc1\n\t"
    "global_load_dwordx4 %4, %6, off offset:256 sc0 sc1\n\t"
    "global_load_dwordx4 %5, %6, off offset:320 sc0 sc1\n\t"
    "s_waitcnt vmcnt(0)"
    : "=&v"(r[0]), "=&v"(r[1]), "=&v"(r[2]), "=&v"(r[3]), "=&v"(r[4]), "=&v"(r[5])
    : "v"(p) : "memory");
}

// stage bf16(x[ts]) slice (8 batches x 256) into LDS xbuf slot; u in [0,128)
__device__ __forceinline__ void stage_x(const float* __restrict__ xsrc,
                                        u16 (*xb)[XBS], int u) {
  #pragma unroll
  for (int i = 0; i < 2; ++i) {
    int cid = u + 128 * i;          // 256 chunks of 8 floats
    int b  = cid >> 5;
    int ko = (cid & 31) * 8;
    const float4* s = (const float4*)(xsrc + (size_t)b * I_ + ko);
    float4 f0 = s[0], f1 = s[1];
    u16x8 uu;
    uu[0]=f2bf(f0.x); uu[1]=f2bf(f0.y); uu[2]=f2bf(f0.z); uu[3]=f2bf(f0.w);
    uu[4]=f2bf(f1.x); uu[5]=f2bf(f1.y); uu[6]=f2bf(f1.z); uu[7]=f2bf(f1.w);
    *(u16x8*)&xb[b][ko] = uu;
  }
}

// Persistent LSTM, 8 chains x 32 WGs (static blockIdx mapping). All cross-WG
// exchange through L3 (sc0|sc1) — no placement assumptions, no discovery, no
// unbounded non-data waits (R5/R6 hang post-mortem: stale-L2 spin on a falsely
// "XCD-local" fast path). Per step: wave w waits only on the 8-12 producer
// flags covering its K-slice, bulk-loads its B-fragments in one L3 RT, MFMAs;
// waves 0,1 also do the elementwise + publish while waves 2,3 pre-stage x.
__global__ __launch_bounds__(BLOCK_MAIN, 1)
void lstm_persistent(const float* __restrict__ x,
                     const float* __restrict__ W_ih,
                     const float* __restrict__ W_hh,
                     const float* __restrict__ b_ih,
                     const float* __restrict__ b_hh,
                     float* __restrict__ out,
                     u32* __restrict__ flags,   // [8][64]
                     u16* __restrict__ ex,      // [2][B_][H_] bf16
                     u16* __restrict__ hist)    // [(T_+1)][B_][H_] bf16
{
  __shared__ __align__(16) u16 xbuf[2][NB][XBS];
  __shared__ float part[4 * 4 * 16 * 17];       // [w][gate][j16][col(+pad)]

  const int tid  = threadIdx.x;
  const int wg   = blockIdx.x;
  const int w    = tid >> 6;        // wave id = K-quarter
  const int lane = tid & 63;
  const int q    = lane >> 4;
  const int n    = lane & 15;
  const int chain = wg & 7;
  const int jslot = wg >> 3;
  const int jbase = jslot * JW;
  const int bbase = chain * NB;

  // ---- W -> register A-fragments (A[m=lane&15][k=q*8+i]), once ----
  bf16x8 afrag[4][6];
  #pragma unroll
  for (int g = 0; g < 4; ++g) {
    #pragma unroll
    for (int kk = 0; kk < 6; ++kk) {
      const int kc  = w * 6 + kk;                 // K-chunk of 32
      const int row = g * H_ + jbase + n;         // gate row in [0,2048)
      const float* src;
      if (kc < 8) src = W_ih + (size_t)row * I_ + kc * 32 + q * 8;
      else        src = W_hh + (size_t)row * H_ + (kc - 8) * 32 + q * 8;
      float4 f0 = ((const float4*)src)[0];
      float4 f1 = ((const float4*)src)[1];
      bf16x8 a;
      a[0]=(__bf16)f0.x; a[1]=(__bf16)f0.y; a[2]=(__bf16)f0.z; a[3]=(__bf16)f0.w;
      a[4]=(__bf16)f1.x; a[5]=(__bf16)f1.y; a[6]=(__bf16)f1.z; a[7]=(__bf16)f1.w;
      afrag[g][kk] = a;
    }
  }

  // ---- elementwise identity: threads 0..127 own (eb in [0,8), ej in [0,16)) ----
  const int eb = tid >> 4;
  const int ej = tid & 15;
  float bias[4];
  float cval = 0.0f;
  if (tid < 128) {
    #pragma unroll
    for (int g = 0; g < 4; ++g)
      bias[g] = b_ih[g * H_ + jbase + ej] + b_hh[g * H_ + jbase + ej];
  }

  const int nx   = (w == 0) ? 6 : ((w == 1) ? 2 : 0);
  const int hoff = (w == 2) ? 128 : ((w == 3) ? 320 : 0);  // first h j-index
  // producer-flag subset for this wave's h K-slice
  const int fbase = (w == 2) ? 8 : ((w == 3) ? 20 : 0);
  const int fcnt  = (w == 1) ? 8 : 12;
  u32* myflags = flags + chain * 64;
  const u32* fp = myflags + fbase + (lane % fcnt);

  // ---- pre-stage x_0 ----
  if (tid >= 128) stage_x(x + (size_t)bbase * I_, xbuf[0], tid - 128);
  __syncthreads();

  for (int t = 0; t < T_; ++t) {
    const int sr = t & 1, sw = (t + 1) & 1;

    bf16x8 bfrag[6];
    #pragma unroll
    for (int kk = 0; kk < 6; ++kk)
      if (kk < nx)
        bfrag[kk] = __builtin_bit_cast(bf16x8,
            *(const uint4*)&xbuf[sr][n & 7][(w * 6 + kk) * 32 + q * 8]);

    if (w > 0) {
      // flag wait: only this wave's producers (8 or 12 flags), L3-served
      for (;;) {
        u32 f = load_u32_l3(fp);
        if (__all((int)(f >= (u32)t))) break;
        __builtin_amdgcn_s_sleep(1);
      }
      // B-fragments straight from ex: one bulk L3 round trip
      const u16* hp = ex + (size_t)sr * BH + (size_t)(bbase + (n & 7)) * H_ +
                      hoff + q * 8;
      if (w == 1) {
        u32x4 r[4];
        load_h4_l3(hp, r);
        #pragma unroll
        for (int i = 0; i < 4; ++i)
          bfrag[2 + i] = __builtin_bit_cast(bf16x8, r[i]);
      } else {
        u32x4 r[6];
        load_h6_l3(hp, r);
        #pragma unroll
        for (int i = 0; i < 6; ++i)
          bfrag[i] = __builtin_bit_cast(bf16x8, r[i]);
      }
    }

    // ---- MFMA partial gates over this wave's K-quarter ----
    floatx4 acc[4] = {};
    #pragma unroll
    for (int kk = 0; kk < 6; ++kk) {
      #pragma unroll
      for (int g = 0; g < 4; ++g)
        acc[g] = __builtin_amdgcn_mfma_f32_16x16x32_bf16(afrag[g][kk], bfrag[kk], acc[g], 0, 0, 0);
    }

    // write partial C tiles (C: col=lane&15=batch, row=q*4+reg=j)
    #pragma unroll
    for (int g = 0; g < 4; ++g)
      #pragma unroll
      for (int r = 0; r < 4; ++r)
        part[((w * 4 + g) * 16 + (q * 4 + r)) * 17 + n] = acc[g][r];
    __syncthreads();

    if (tid < 128) {
      // ---- reduce 4 K-partials, gates -> c,h ; publish h (u32-paired) ----
      float gate[4];
      #pragma unroll
      for (int g = 0; g < 4; ++g) {
        float s = bias[g];
        #pragma unroll
        for (int w2 = 0; w2 < 4; ++w2)
          s += part[((w2 * 4 + g) * 16 + ej) * 17 + eb];
        gate[g] = s;
      }
      const float ig = sigmoid_f(gate[0]);
      const float fg = sigmoid_f(gate[1]);
      const float gg = tanh_f(gate[2]);
      const float og = sigmoid_f(gate[3]);
      cval = fg * cval + ig * gg;
      const float hval = og * tanh_f(cval);
      const int bg = bbase + eb;
      const int jg = jbase + ej;
      // pair adjacent ej via shuffle; even thread stores the u32
      const u32 hb = (u32)f2bf(hval);
      const u32 other = __shfl_xor((int)hb, 1, 64);
      if ((tid & 1) == 0) {
        const u32 packed = hb | (other << 16);
        store_u32_l3((u32*)(ex + (size_t)sw * BH + (size_t)bg * H_ + jg), packed);
        *(u32*)(hist + (size_t)(t + 1) * BH + (size_t)bg * H_ + jg) = packed;
      }
      if (t == T_ - 1) {
        out[TBO + (size_t)bg * H_ + jg]      = hval;   // h_T
        out[TBO + BH + (size_t)bg * H_ + jg] = cval;   // c_T
      }
    } else {
      // ---- waves 2,3: pre-stage x_{t+1} ----
      const int ts = (t + 1 < T_) ? (t + 1) : (T_ - 1);
      stage_x(x + ((size_t)ts * B_ + bbase) * I_, xbuf[sw], tid - 128);
    }
    __syncthreads();   // drains h stores (vmcnt) before the flag store
    if (tid == 0)
      store_u32_l3(&myflags[jslot], (u32)(t + 1));
  }
}

// outputs[t,b,:] = h_t @ fc_w^T + fc_b ; one wave per (t,b) row
__global__ __launch_bounds__(256)
void fc_kernel(const u16* __restrict__ hist,
               const float* __restrict__ fc_w,
               const float* __restrict__ fc_b,
               float* __restrict__ out)
{
  const int gw   = (blockIdx.x * 256 + threadIdx.x) >> 6;
  const int lane = threadIdx.x & 63;
  const int t = gw >> 6;
  const int b = gw & 63;
  const u16* hrow = hist + ((size_t)(t + 1) * B_ + b) * H_ + lane * 8;
  uint4 hv = *(const uint4*)hrow;
  float h[8];
  {
    u16x8 hu = __builtin_bit_cast(u16x8, hv);
    #pragma unroll
    for (int i = 0; i < 8; ++i) h[i] = bf2f(hu[i]);
  }
  float accs[O_];
  #pragma unroll
  for (int o = 0; o < O_; ++o) {
    const float* wr = fc_w + (size_t)o * H_ + lane * 8;
    float4 w0 = ((const float4*)wr)[0];
    float4 w1 = ((const float4*)wr)[1];
    accs[o] = h[0]*w0.x + h[1]*w0.y + h[2]*w0.z + h[3]*w0.w
            + h[4]*w1.x + h[5]*w1.y + h[6]*w1.z + h[7]*w1.w;
  }
  #pragma unroll
  for (int o = 0; o < O_; ++o)
    #pragma unroll
    for (int off = 32; off > 0; off >>= 1)
      accs[o] += __shfl_down(accs[o], off, 64);
  if (lane == 0) {
    #pragma unroll
    for (int o = 0; o < O_; ++o)
      out[((size_t)t * B_ + b) * O_ + o] = accs[o] + fc_b[o];
  }
}

extern "C" void kernel_launch(void* const* d_in, const int* in_sizes, int n_in,
                              void* d_out, int out_size, void* d_ws, size_t ws_size,
                              hipStream_t stream)
{
  (void)in_sizes; (void)n_in; (void)out_size; (void)ws_size;
  const float* x    = (const float*)d_in[0];
  const float* W_ih = (const float*)d_in[1];
  const float* W_hh = (const float*)d_in[2];
  const float* b_ih = (const float*)d_in[3];
  const float* b_hh = (const float*)d_in[4];
  const float* fc_w = (const float*)d_in[5];
  const float* fc_b = (const float*)d_in[6];
  float* out = (float*)d_out;

  u32* flags = (u32*)d_ws;                              // [8][64] = 2 KB
  u16* ex    = (u16*)((char*)d_ws + EX_OFF);            // 2*BH bf16 = 128 KB
  u16* hist  = (u16*)((char*)d_ws + EX_OFF + 2 * BH * 2);

  // zero flags + both ex slots (slot0 = h_0 = 0; clears 0xAA poison)
  hipMemsetAsync(d_ws, 0, EX_OFF + 2 * BH * 2, stream);

  lstm_persistent<<<GRID_MAIN, BLOCK_MAIN, 0, stream>>>(
      x, W_ih, W_hh, b_ih, b_hh, out, flags, ex, hist);
  fc_kernel<<<(T_ * B_) / 4, 256, 0, stream>>>(hist, fc_w, fc_b, out);
}